// Round 5
// baseline (660.038 us; speedup 1.0000x reference)
//
#include <hip/hip_runtime.h>
#include <math.h>

// Problem constants (fixed by the reference setup)
constexpr int KH_ = 8;            // kv heads
constexpr int G_ = 4;             // q heads per kv head (H/KH = 32/8)
constexpr int D_ = 128;           // head dim
constexpr int KHD_ = KH_ * D_;    // 1024, row stride of k/v pool per token
constexpr int HD_ = 32 * 128;     // 4096, q/out row stride per request
constexpr int WAVES = 16;
constexpr int BLOCK = WAVES * 64; // 1024 threads

__global__ void scatter_kv_kernel(const float* __restrict__ k, const float* __restrict__ v,
                                  float* __restrict__ kb, float* __restrict__ vb,
                                  const int* __restrict__ loc, int n) {
    int i = blockIdx.x * blockDim.x + threadIdx.x;
    if (i < n) {
        int b = i / KHD_;
        int off = i - b * KHD_;
        size_t dst = (size_t)loc[b] * KHD_ + off;
        kb[dst] = k[i];
        vb[dst] = v[i];
    }
}

__global__ __launch_bounds__(BLOCK) void attn_decode_kernel(
    const float* __restrict__ q,
    const float* __restrict__ kb,
    const float* __restrict__ vb,
    const int* __restrict__ req_to_token,
    const int* __restrict__ req_pool_indices,
    const int* __restrict__ seq_lens,
    int srt,
    float* __restrict__ out) {
    // LDS
    __shared__ float4 q4[G_ * 32];          // scaled q rows: [g*32 + j]
    __shared__ float4 p4[WAVES][64];        // per-wave p: [token-in-chunk] -> (p0,p1,p2,p3)
    __shared__ int    tokl[WAVES][64];      // per-wave token pool indices for current chunk
    __shared__ float4 wacc[WAVES][G_][32];  // per-wave partial acc
    __shared__ float  wm[WAVES][G_];
    __shared__ float  wl[WAVES][G_];

    const int bid = blockIdx.x;
    const int b = bid / KH_;
    const int kh = bid - b * KH_;
    const int tid = threadIdx.x;
    const int wave = tid >> 6;
    const int lane = tid & 63;

    const int S = seq_lens[b];
    const int rp = req_pool_indices[b];
    const int* __restrict__ tokrow = req_to_token + (size_t)rp * srt;

    const float scale = 0.08838834764831845f; // 1/sqrt(128)

    // Load q (4 heads x 128) into LDS, pre-scaled.
    if (tid < G_ * 32) {
        const float4* qsrc = (const float4*)(q + (size_t)b * HD_ + (size_t)(kh * G_) * D_);
        float4 t = qsrc[tid];
        t.x *= scale; t.y *= scale; t.z *= scale; t.w *= scale;
        q4[tid] = t;
    }
    __syncthreads();

    float m0 = -INFINITY, m1 = -INFINITY, m2 = -INFINITY, m3 = -INFINITY;
    float l0 = 0.f, l1 = 0.f, l2 = 0.f, l3 = 0.f;
    float4 a0 = {0,0,0,0}, a1 = {0,0,0,0}, a2 = {0,0,0,0}, a3 = {0,0,0,0};

    const int NC = (S + 63) >> 6;
    const int half = lane >> 5;   // token parity for PV phase
    const int dq = lane & 31;     // d-quad for PV phase

    for (int c = wave; c < NC; c += WAVES) {
        const int s = (c << 6) + lane;
        const bool valid = s < S;
        const int tok = tokrow[valid ? s : (S - 1)];
        tokl[wave][lane] = tok;

        // ---- Phase 1: QK^T, lane owns one token, lane-local dot over d ----
        const float4* kp = (const float4*)(kb + (size_t)tok * (size_t)KHD_ + (size_t)(kh * D_));
        float s0 = 0.f, s1 = 0.f, s2 = 0.f, s3 = 0.f;
        #pragma unroll 4
        for (int j = 0; j < 32; ++j) {
            const float4 kv = kp[j];
            const float4 qa = q4[j];
            const float4 qb = q4[32 + j];
            const float4 qc = q4[64 + j];
            const float4 qd = q4[96 + j];
            s0 += qa.x*kv.x + qa.y*kv.y + qa.z*kv.z + qa.w*kv.w;
            s1 += qb.x*kv.x + qb.y*kv.y + qb.z*kv.z + qb.w*kv.w;
            s2 += qc.x*kv.x + qc.y*kv.y + qc.z*kv.z + qc.w*kv.w;
            s3 += qd.x*kv.x + qd.y*kv.y + qd.z*kv.z + qd.w*kv.w;
        }
        if (!valid) { s0 = -INFINITY; s1 = -INFINITY; s2 = -INFINITY; s3 = -INFINITY; }

        // ---- Online softmax (per-wave, per-g) ----
        float c0 = s0, c1 = s1, c2 = s2, c3 = s3;
        #pragma unroll
        for (int off = 32; off > 0; off >>= 1) {
            c0 = fmaxf(c0, __shfl_xor(c0, off));
            c1 = fmaxf(c1, __shfl_xor(c1, off));
            c2 = fmaxf(c2, __shfl_xor(c2, off));
            c3 = fmaxf(c3, __shfl_xor(c3, off));
        }
        const float n0 = fmaxf(m0, c0), n1 = fmaxf(m1, c1), n2 = fmaxf(m2, c2), n3 = fmaxf(m3, c3);
        const float r0 = __expf(m0 - n0), r1 = __expf(m1 - n1), r2 = __expf(m2 - n2), r3 = __expf(m3 - n3);
        m0 = n0; m1 = n1; m2 = n2; m3 = n3;
        float p0 = valid ? __expf(s0 - n0) : 0.f;
        float p1 = valid ? __expf(s1 - n1) : 0.f;
        float p2 = valid ? __expf(s2 - n2) : 0.f;
        float p3 = valid ? __expf(s3 - n3) : 0.f;
        float t0 = p0, t1 = p1, t2s = p2, t3 = p3;
        #pragma unroll
        for (int off = 32; off > 0; off >>= 1) {
            t0 += __shfl_xor(t0, off);
            t1 += __shfl_xor(t1, off);
            t2s += __shfl_xor(t2s, off);
            t3 += __shfl_xor(t3, off);
        }
        l0 = l0 * r0 + t0; l1 = l1 * r1 + t1; l2 = l2 * r2 + t2s; l3 = l3 * r3 + t3;
        p4[wave][lane] = make_float4(p0, p1, p2, p3);

        // rescale accumulators (r is wave-uniform)
        a0.x *= r0; a0.y *= r0; a0.z *= r0; a0.w *= r0;
        a1.x *= r1; a1.y *= r1; a1.z *= r1; a1.w *= r1;
        a2.x *= r2; a2.y *= r2; a2.z *= r2; a2.w *= r2;
        a3.x *= r3; a3.y *= r3; a3.z *= r3; a3.w *= r3;

        // ---- Phase 2: PV, lanes own d-quads; two tokens/iter via lane halves ----
        #pragma unroll 4
        for (int t2 = 0; t2 < 32; ++t2) {
            const int idx = (t2 << 1) + half;
            const int tv = tokl[wave][idx];
            const float4 vv = *(const float4*)(vb + (size_t)tv * (size_t)KHD_ + (size_t)(kh * D_) + (dq << 2));
            const float4 pv = p4[wave][idx];
            a0.x += pv.x * vv.x; a0.y += pv.x * vv.y; a0.z += pv.x * vv.z; a0.w += pv.x * vv.w;
            a1.x += pv.y * vv.x; a1.y += pv.y * vv.y; a1.z += pv.y * vv.z; a1.w += pv.y * vv.w;
            a2.x += pv.z * vv.x; a2.y += pv.z * vv.y; a2.z += pv.z * vv.z; a2.w += pv.z * vv.w;
            a3.x += pv.w * vv.x; a3.y += pv.w * vv.y; a3.z += pv.w * vv.z; a3.w += pv.w * vv.w;
        }
    }

    // Combine parity halves (tokens even/odd) within the wave.
    a0.x += __shfl_xor(a0.x, 32); a0.y += __shfl_xor(a0.y, 32); a0.z += __shfl_xor(a0.z, 32); a0.w += __shfl_xor(a0.w, 32);
    a1.x += __shfl_xor(a1.x, 32); a1.y += __shfl_xor(a1.y, 32); a1.z += __shfl_xor(a1.z, 32); a1.w += __shfl_xor(a1.w, 32);
    a2.x += __shfl_xor(a2.x, 32); a2.y += __shfl_xor(a2.y, 32); a2.z += __shfl_xor(a2.z, 32); a2.w += __shfl_xor(a2.w, 32);
    a3.x += __shfl_xor(a3.x, 32); a3.y += __shfl_xor(a3.y, 32); a3.z += __shfl_xor(a3.z, 32); a3.w += __shfl_xor(a3.w, 32);

    if (lane < 32) {
        wacc[wave][0][dq] = a0;
        wacc[wave][1][dq] = a1;
        wacc[wave][2][dq] = a2;
        wacc[wave][3][dq] = a3;
    }
    if (lane == 0) {
        wm[wave][0] = m0; wm[wave][1] = m1; wm[wave][2] = m2; wm[wave][3] = m3;
        wl[wave][0] = l0; wl[wave][1] = l1; wl[wave][2] = l2; wl[wave][3] = l3;
    }
    __syncthreads();

    // Final combine across waves: 128 threads produce 4 heads x 128 dims.
    if (tid < 128) {
        const int g = tid >> 5;
        const int dqq = tid & 31;
        float M = -INFINITY;
        #pragma unroll
        for (int w = 0; w < WAVES; ++w) M = fmaxf(M, wm[w][g]);
        float L = 0.f;
        float4 o = {0,0,0,0};
        #pragma unroll
        for (int w = 0; w < WAVES; ++w) {
            const float f = __expf(wm[w][g] - M);
            L += f * wl[w][g];
            const float4 a = wacc[w][g][dqq];
            o.x += f * a.x; o.y += f * a.y; o.z += f * a.z; o.w += f * a.w;
        }
        const float inv = 1.f / L;
        float4 res;
        res.x = o.x * inv; res.y = o.y * inv; res.z = o.z * inv; res.w = o.w * inv;
        *((float4*)(out + (size_t)b * HD_ + (size_t)(kh * G_ + g) * D_ + (dqq << 2))) = res;
    }
}

extern "C" void kernel_launch(void* const* d_in, const int* in_sizes, int n_in,
                              void* d_out, int out_size, void* d_ws, size_t ws_size,
                              hipStream_t stream) {
    const float* q  = (const float*)d_in[0];
    const float* k  = (const float*)d_in[1];
    const float* v  = (const float*)d_in[2];
    float* kb       = (float*)d_in[3];   // scatter target; harness restores inputs each launch
    float* vb       = (float*)d_in[4];
    const int* req_to_token     = (const int*)d_in[5];
    const int* req_pool_indices = (const int*)d_in[6];
    const int* out_cache_loc    = (const int*)d_in[7];
    const int* seq_lens         = (const int*)d_in[8];
    float* out = (float*)d_out;

    const int Bn = in_sizes[6];              // 32 requests
    const int nscatter = in_sizes[1];        // B*KH*D = 32768
    const int srt = in_sizes[5] / Bn;        // req_to_token row stride = 2049

    scatter_kv_kernel<<<(nscatter + 255) / 256, 256, 0, stream>>>(k, v, kb, vb, out_cache_loc, nscatter);
    attn_decode_kernel<<<Bn * KH_, BLOCK, 0, stream>>>(q, kb, vb, req_to_token, req_pool_indices,
                                                       seq_lens, srt, out);
}

// Round 7
// 550.870 us; speedup vs baseline: 1.1982x; 1.1982x over previous
//
#include <hip/hip_runtime.h>
#include <math.h>

// Problem constants (fixed by the reference setup)
constexpr int KH_ = 8;            // kv heads
constexpr int G_ = 4;             // q heads per kv head (H/KH = 32/8)
constexpr int D_ = 128;           // head dim
constexpr int KHD_ = KH_ * D_;    // 1024, row stride of k/v pool per token (floats)
constexpr int HD_ = 32 * 128;     // 4096, q/out row stride per request (floats)
constexpr int SLOT_F = 132;       // floats per (kh,g) partial slot: [m,l,pad,pad,acc128]

__global__ void scatter_kv_kernel(const float* __restrict__ k, const float* __restrict__ v,
                                  float* __restrict__ kb, float* __restrict__ vb,
                                  const int* __restrict__ loc, int n) {
    int i = blockIdx.x * blockDim.x + threadIdx.x;
    if (i < n) {
        int b = i / KHD_;
        int off = i - b * KHD_;
        size_t dst = (size_t)loc[b] * KHD_ + off;
        kb[dst] = k[i];
        vb[dst] = v[i];
    }
}

// ---------------------------------------------------------------------------
// Split-S flash-decoding. Block = (request b, token slice c of tpb tokens).
// 256 threads: thread T -> kh = T>>5, dq = T&31 (d-quad within the head dim).
// Per token the block reads the FULL contiguous 4KB K row (each wave 1KB),
// so DRAM sees pure sequential streams (no 512B/4KB striding).
// Scores reduced with __shfl_xor over the 32-lane d-group; partial softmax
// per slice; V pass identical; partials (m,l,acc[128]) per (kh,g) -> ws.
// ---------------------------------------------------------------------------
__global__ __launch_bounds__(256, 6) void attn_partial_kernel(
    const float* __restrict__ q,
    const float* __restrict__ kb,
    const float* __restrict__ vb,
    const int* __restrict__ req_to_token,
    const int* __restrict__ req_pool_indices,
    const int* __restrict__ seq_lens,
    int srt, int tpb, int nsl,
    float* __restrict__ ws) {
    extern __shared__ float sc[];   // [tpb][32]  scores/p: slot = kh*4+g

    const int bid = blockIdx.x;
    const int b = bid / nsl;
    const int c = bid - b * nsl;
    const int T = threadIdx.x;
    const int kh = T >> 5;
    const int dq = T & 31;

    const int S = seq_lens[b];
    const int rp = req_pool_indices[b];
    const int* __restrict__ tokrow = req_to_token + (size_t)rp * srt;
    const int t0 = c * tpb;
    int ntok = S - t0;
    if (ntok > tpb) ntok = tpb;
    if (ntok < 0) ntok = 0;

    const float scale = 0.08838834764831845f; // 1/sqrt(128)
    // q fragments for this thread's (kh, d-quad), all 4 g heads, pre-scaled.
    const float* qp = q + (size_t)b * HD_ + (size_t)(kh * G_) * D_ + (dq << 2);
    float4 q0 = *(const float4*)(qp);
    float4 q1 = *(const float4*)(qp + D_);
    float4 q2 = *(const float4*)(qp + 2 * D_);
    float4 q3 = *(const float4*)(qp + 3 * D_);
    q0.x *= scale; q0.y *= scale; q0.z *= scale; q0.w *= scale;
    q1.x *= scale; q1.y *= scale; q1.z *= scale; q1.w *= scale;
    q2.x *= scale; q2.y *= scale; q2.z *= scale; q2.w *= scale;
    q3.x *= scale; q3.y *= scale; q3.z *= scale; q3.w *= scale;

    // ---- Phase A: QK^T over the slice; full contiguous K rows ----
    #pragma unroll 2
    for (int t = 0; t < ntok; ++t) {
        const int tok = tokrow[t0 + t];
        const float4 kv = *(const float4*)(kb + (size_t)tok * KHD_ + kh * D_ + (dq << 2));
        float p0 = q0.x * kv.x + q0.y * kv.y + q0.z * kv.z + q0.w * kv.w;
        float p1 = q1.x * kv.x + q1.y * kv.y + q1.z * kv.z + q1.w * kv.w;
        float p2 = q2.x * kv.x + q2.y * kv.y + q2.z * kv.z + q2.w * kv.w;
        float p3 = q3.x * kv.x + q3.y * kv.y + q3.z * kv.z + q3.w * kv.w;
        #pragma unroll
        for (int off = 16; off > 0; off >>= 1) {
            p0 += __shfl_xor(p0, off);
            p1 += __shfl_xor(p1, off);
            p2 += __shfl_xor(p2, off);
            p3 += __shfl_xor(p3, off);
        }
        if (dq == 0) *(float4*)&sc[(t << 5) + (kh << 2)] = make_float4(p0, p1, p2, p3);
    }
    __syncthreads();

    // ---- Partial softmax per (kh,g): m, l; overwrite scores with p ----
    if (T < 32) {
        float m = -INFINITY;
        for (int t = 0; t < ntok; ++t) m = fmaxf(m, sc[(t << 5) + T]);
        float l = 0.f;
        for (int t = 0; t < ntok; ++t) {
            const float p = __expf(sc[(t << 5) + T] - m);
            l += p;
            sc[(t << 5) + T] = p;
        }
        float* wsl = ws + ((size_t)bid * 32 + T) * SLOT_F;
        wsl[0] = m;
        wsl[1] = l;
    }
    __syncthreads();

    // ---- Phase B: PV; full contiguous V rows ----
    float4 a0 = {0,0,0,0}, a1 = {0,0,0,0}, a2 = {0,0,0,0}, a3 = {0,0,0,0};
    #pragma unroll 2
    for (int t = 0; t < ntok; ++t) {
        const int tok = tokrow[t0 + t];
        const float4 vv = *(const float4*)(vb + (size_t)tok * KHD_ + kh * D_ + (dq << 2));
        const float4 pp = *(const float4*)&sc[(t << 5) + (kh << 2)];
        a0.x += pp.x * vv.x; a0.y += pp.x * vv.y; a0.z += pp.x * vv.z; a0.w += pp.x * vv.w;
        a1.x += pp.y * vv.x; a1.y += pp.y * vv.y; a1.z += pp.y * vv.z; a1.w += pp.y * vv.w;
        a2.x += pp.z * vv.x; a2.y += pp.z * vv.y; a2.z += pp.z * vv.z; a2.w += pp.z * vv.w;
        a3.x += pp.w * vv.x; a3.y += pp.w * vv.y; a3.z += pp.w * vv.z; a3.w += pp.w * vv.w;
    }

    float* wsb = ws + (size_t)bid * 32 * SLOT_F + (size_t)(kh << 2) * SLOT_F + 4 + (dq << 2);
    *(float4*)(wsb)              = a0;
    *(float4*)(wsb + SLOT_F)     = a1;
    *(float4*)(wsb + 2 * SLOT_F) = a2;
    *(float4*)(wsb + 3 * SLOT_F) = a3;
}

// Combine nsl slice-partials per (b,kh): block = b*KH+kh, thread = (g, dq).
__global__ __launch_bounds__(128) void attn_combine_kernel(
    const float* __restrict__ ws, float* __restrict__ out, int nsl) {
    const int bid = blockIdx.x;          // b*8 + kh
    const int b = bid >> 3;
    const int kh = bid & 7;
    const int T = threadIdx.x;
    const int g = T >> 5;
    const int dq = T & 31;
    const size_t slot0 = (size_t)b * nsl * 32 + (kh << 2) + g;

    float M = -INFINITY;
    for (int c = 0; c < nsl; ++c)
        M = fmaxf(M, ws[(slot0 + (size_t)c * 32) * SLOT_F]);
    float L = 0.f;
    float4 o = {0,0,0,0};
    for (int c = 0; c < nsl; ++c) {
        const float* w = ws + (slot0 + (size_t)c * 32) * SLOT_F;
        const float f = __expf(w[0] - M);   // m=-INF (empty slice) -> f=0
        L += f * w[1];
        const float4 a = *(const float4*)(w + 4 + (dq << 2));
        o.x += f * a.x; o.y += f * a.y; o.z += f * a.z; o.w += f * a.w;
    }
    const float inv = 1.f / L;
    *(float4*)(out + (size_t)b * HD_ + (size_t)((kh << 2) + g) * D_ + (dq << 2)) =
        make_float4(o.x * inv, o.y * inv, o.z * inv, o.w * inv);
}

// ---------------------------------------------------------------------------
// Fallback (round-5 kernel) if ws is too small for the split-S path.
// ---------------------------------------------------------------------------
constexpr int WAVES = 16;
constexpr int BLOCK = WAVES * 64;

__global__ __launch_bounds__(BLOCK) void attn_decode_kernel(
    const float* __restrict__ q,
    const float* __restrict__ kb,
    const float* __restrict__ vb,
    const int* __restrict__ req_to_token,
    const int* __restrict__ req_pool_indices,
    const int* __restrict__ seq_lens,
    int srt,
    float* __restrict__ out) {
    __shared__ float4 q4[G_ * 32];
    __shared__ float4 p4[WAVES][64];
    __shared__ int    tokl[WAVES][64];
    __shared__ float4 wacc[WAVES][G_][32];
    __shared__ float  wm[WAVES][G_];
    __shared__ float  wl[WAVES][G_];

    const int bid = blockIdx.x;
    const int b = bid / KH_;
    const int kh = bid - b * KH_;
    const int tid = threadIdx.x;
    const int wave = tid >> 6;
    const int lane = tid & 63;

    const int S = seq_lens[b];
    const int rp = req_pool_indices[b];
    const int* __restrict__ tokrow = req_to_token + (size_t)rp * srt;
    const float scale = 0.08838834764831845f;

    if (tid < G_ * 32) {
        const float4* qsrc = (const float4*)(q + (size_t)b * HD_ + (size_t)(kh * G_) * D_);
        float4 t = qsrc[tid];
        t.x *= scale; t.y *= scale; t.z *= scale; t.w *= scale;
        q4[tid] = t;
    }
    __syncthreads();

    float m0 = -INFINITY, m1 = -INFINITY, m2 = -INFINITY, m3 = -INFINITY;
    float l0 = 0.f, l1 = 0.f, l2 = 0.f, l3 = 0.f;
    float4 a0 = {0,0,0,0}, a1 = {0,0,0,0}, a2 = {0,0,0,0}, a3 = {0,0,0,0};
    const int NC = (S + 63) >> 6;
    const int half = lane >> 5;
    const int dq = lane & 31;

    for (int c = wave; c < NC; c += WAVES) {
        const int s = (c << 6) + lane;
        const bool valid = s < S;
        const int tok = tokrow[valid ? s : (S - 1)];
        tokl[wave][lane] = tok;
        const float4* kp = (const float4*)(kb + (size_t)tok * (size_t)KHD_ + (size_t)(kh * D_));
        float s0 = 0.f, s1 = 0.f, s2 = 0.f, s3 = 0.f;
        #pragma unroll 4
        for (int j = 0; j < 32; ++j) {
            const float4 kv = kp[j];
            const float4 qa = q4[j];
            const float4 qb = q4[32 + j];
            const float4 qc = q4[64 + j];
            const float4 qd = q4[96 + j];
            s0 += qa.x*kv.x + qa.y*kv.y + qa.z*kv.z + qa.w*kv.w;
            s1 += qb.x*kv.x + qb.y*kv.y + qb.z*kv.z + qb.w*kv.w;
            s2 += qc.x*kv.x + qc.y*kv.y + qc.z*kv.z + qc.w*kv.w;
            s3 += qd.x*kv.x + qd.y*kv.y + qd.z*kv.z + qd.w*kv.w;
        }
        if (!valid) { s0 = -INFINITY; s1 = -INFINITY; s2 = -INFINITY; s3 = -INFINITY; }
        float c0 = s0, c1 = s1, c2 = s2, c3 = s3;
        #pragma unroll
        for (int off = 32; off > 0; off >>= 1) {
            c0 = fmaxf(c0, __shfl_xor(c0, off));
            c1 = fmaxf(c1, __shfl_xor(c1, off));
            c2 = fmaxf(c2, __shfl_xor(c2, off));
            c3 = fmaxf(c3, __shfl_xor(c3, off));
        }
        const float n0 = fmaxf(m0, c0), n1 = fmaxf(m1, c1), n2 = fmaxf(m2, c2), n3 = fmaxf(m3, c3);
        const float r0 = __expf(m0 - n0), r1 = __expf(m1 - n1), r2 = __expf(m2 - n2), r3 = __expf(m3 - n3);
        m0 = n0; m1 = n1; m2 = n2; m3 = n3;
        float p0 = valid ? __expf(s0 - n0) : 0.f;
        float p1 = valid ? __expf(s1 - n1) : 0.f;
        float p2 = valid ? __expf(s2 - n2) : 0.f;
        float p3 = valid ? __expf(s3 - n3) : 0.f;
        float t0 = p0, t1 = p1, t2s = p2, t3 = p3;
        #pragma unroll
        for (int off = 32; off > 0; off >>= 1) {
            t0 += __shfl_xor(t0, off);
            t1 += __shfl_xor(t1, off);
            t2s += __shfl_xor(t2s, off);
            t3 += __shfl_xor(t3, off);
        }
        l0 = l0 * r0 + t0; l1 = l1 * r1 + t1; l2 = l2 * r2 + t2s; l3 = l3 * r3 + t3;
        p4[wave][lane] = make_float4(p0, p1, p2, p3);
        a0.x *= r0; a0.y *= r0; a0.z *= r0; a0.w *= r0;
        a1.x *= r1; a1.y *= r1; a1.z *= r1; a1.w *= r1;
        a2.x *= r2; a2.y *= r2; a2.z *= r2; a2.w *= r2;
        a3.x *= r3; a3.y *= r3; a3.z *= r3; a3.w *= r3;
        #pragma unroll 4
        for (int t2 = 0; t2 < 32; ++t2) {
            const int idx = (t2 << 1) + half;
            const int tv = tokl[wave][idx];
            const float4 vv = *(const float4*)(vb + (size_t)tv * (size_t)KHD_ + (size_t)(kh * D_) + (dq << 2));
            const float4 pv = p4[wave][idx];
            a0.x += pv.x * vv.x; a0.y += pv.x * vv.y; a0.z += pv.x * vv.z; a0.w += pv.x * vv.w;
            a1.x += pv.y * vv.x; a1.y += pv.y * vv.y; a1.z += pv.y * vv.z; a1.w += pv.y * vv.w;
            a2.x += pv.z * vv.x; a2.y += pv.z * vv.y; a2.z += pv.z * vv.z; a2.w += pv.z * vv.w;
            a3.x += pv.w * vv.x; a3.y += pv.w * vv.y; a3.z += pv.w * vv.z; a3.w += pv.w * vv.w;
        }
    }
    a0.x += __shfl_xor(a0.x, 32); a0.y += __shfl_xor(a0.y, 32); a0.z += __shfl_xor(a0.z, 32); a0.w += __shfl_xor(a0.w, 32);
    a1.x += __shfl_xor(a1.x, 32); a1.y += __shfl_xor(a1.y, 32); a1.z += __shfl_xor(a1.z, 32); a1.w += __shfl_xor(a1.w, 32);
    a2.x += __shfl_xor(a2.x, 32); a2.y += __shfl_xor(a2.y, 32); a2.z += __shfl_xor(a2.z, 32); a2.w += __shfl_xor(a2.w, 32);
    a3.x += __shfl_xor(a3.x, 32); a3.y += __shfl_xor(a3.y, 32); a3.z += __shfl_xor(a3.z, 32); a3.w += __shfl_xor(a3.w, 32);
    if (lane < 32) {
        wacc[wave][0][dq] = a0;
        wacc[wave][1][dq] = a1;
        wacc[wave][2][dq] = a2;
        wacc[wave][3][dq] = a3;
    }
    if (lane == 0) {
        wm[wave][0] = m0; wm[wave][1] = m1; wm[wave][2] = m2; wm[wave][3] = m3;
        wl[wave][0] = l0; wl[wave][1] = l1; wl[wave][2] = l2; wl[wave][3] = l3;
    }
    __syncthreads();
    if (tid < 128) {
        const int g = tid >> 5;
        const int dqq = tid & 31;
        float M = -INFINITY;
        #pragma unroll
        for (int w = 0; w < WAVES; ++w) M = fmaxf(M, wm[w][g]);
        float L = 0.f;
        float4 o = {0,0,0,0};
        #pragma unroll
        for (int w = 0; w < WAVES; ++w) {
            const float f = __expf(wm[w][g] - M);
            L += f * wl[w][g];
            const float4 a = wacc[w][g][dqq];
            o.x += f * a.x; o.y += f * a.y; o.z += f * a.z; o.w += f * a.w;
        }
        const float inv = 1.f / L;
        *((float4*)(out + (size_t)b * HD_ + (size_t)(kh * G_ + g) * D_ + (dqq << 2))) =
            make_float4(o.x * inv, o.y * inv, o.z * inv, o.w * inv);
    }
}

extern "C" void kernel_launch(void* const* d_in, const int* in_sizes, int n_in,
                              void* d_out, int out_size, void* d_ws, size_t ws_size,
                              hipStream_t stream) {
    const float* q  = (const float*)d_in[0];
    const float* k  = (const float*)d_in[1];
    const float* v  = (const float*)d_in[2];
    float* kb       = (float*)d_in[3];
    float* vb       = (float*)d_in[4];
    const int* req_to_token     = (const int*)d_in[5];
    const int* req_pool_indices = (const int*)d_in[6];
    const int* out_cache_loc    = (const int*)d_in[7];
    const int* seq_lens         = (const int*)d_in[8];
    float* out = (float*)d_out;

    const int Bn = in_sizes[6];              // 32 requests
    const int nscatter = in_sizes[1];        // B*KH*D = 32768
    const int srt = in_sizes[5] / Bn;        // req_to_token row stride = 2049

    scatter_kv_kernel<<<(nscatter + 255) / 256, 256, 0, stream>>>(k, v, kb, vb, out_cache_loc, nscatter);

    // Pick the smallest slice size (max parallelism) whose partials fit d_ws.
    int tpb = 0, nsl = 0;
    for (int cand = 32; cand <= 512; cand <<= 1) {
        const int n = (srt + cand - 1) / cand;
        const size_t need = (size_t)Bn * n * 32 * (SLOT_F * sizeof(float));
        if (need <= ws_size) { tpb = cand; nsl = n; break; }
    }

    if (tpb) {
        const size_t lds = (size_t)tpb * 32 * sizeof(float);
        attn_partial_kernel<<<Bn * nsl, 256, lds, stream>>>(
            q, kb, vb, req_to_token, req_pool_indices, seq_lens, srt, tpb, nsl, (float*)d_ws);
        attn_combine_kernel<<<Bn * KH_, 128, 0, stream>>>((const float*)d_ws, out, nsl);
    } else {
        attn_decode_kernel<<<Bn * KH_, BLOCK, 0, stream>>>(
            q, kb, vb, req_to_token, req_pool_indices, seq_lens, srt, out);
    }
}